// Round 5
// baseline (237.447 us; speedup 1.0000x reference)
//
#include <hip/hip_runtime.h>
#include <hip/hip_bf16.h>

#define BB   64      // batch
#define MM   512     // memories
#define SS   1024    // story len
#define EE   128     // embed
#define CC   10000   // classes
#define KCH  16      // m-chunks for stories reduction
#define MCH  (MM / KCH)   // 32 rows per chunk
#define CTILE 16     // classes per block in logits kernel (10000 = 625*16)

__device__ __forceinline__ float dot4(const float4 a, const float4 b) {
    return a.x * b.x + a.y * b.y + a.z * b.z + a.w * b.w;
}

// ---------------------------------------------------------------------------
// Kernel 1: blocks [0,1024): partial[k][b][s] = sum over m-chunk k of stories.
//           blocks [1024,1152): u0 rows — uo[b][r] = dot(W1[r], q[b]).
// The u0 compute (8.4M MAC, L2-resident W1) hides under the 134 MB HBM stream.
// ---------------------------------------------------------------------------
__global__ __launch_bounds__(256) void k_stories_u0(
    const float4* __restrict__ stories, float4* __restrict__ partial,
    const float* __restrict__ queries, const float* __restrict__ W1,
    float* __restrict__ uo) {
    const int S4 = SS / 4;  // 256
    const int blk = blockIdx.x;
    const int t = threadIdx.x;

    if (blk < BB * KCH) {
        const int b = blk >> 4;          // / KCH
        const int k = blk & (KCH - 1);
        const float4* src = stories + ((size_t)(b * MM + k * MCH) * S4 + t);
        float4 a0 = make_float4(0.f, 0.f, 0.f, 0.f);
        float4 a1 = a0, a2 = a0, a3 = a0;
        #pragma unroll
        for (int m = 0; m < MCH; m += 4) {
            float4 x0 = src[(size_t)(m + 0) * S4];
            float4 x1 = src[(size_t)(m + 1) * S4];
            float4 x2 = src[(size_t)(m + 2) * S4];
            float4 x3 = src[(size_t)(m + 3) * S4];
            a0.x += x0.x; a0.y += x0.y; a0.z += x0.z; a0.w += x0.w;
            a1.x += x1.x; a1.y += x1.y; a1.z += x1.z; a1.w += x1.w;
            a2.x += x2.x; a2.y += x2.y; a2.z += x2.z; a2.w += x2.w;
            a3.x += x3.x; a3.y += x3.y; a3.z += x3.z; a3.w += x3.w;
        }
        float4 r;
        r.x = (a0.x + a1.x) + (a2.x + a3.x);
        r.y = (a0.y + a1.y) + (a2.y + a3.y);
        r.z = (a0.z + a1.z) + (a2.z + a3.z);
        r.w = (a0.w + a1.w) + (a2.w + a3.w);
        partial[(size_t)(k * BB + b) * S4 + t] = r;
    } else {
        __shared__ float q_sh[SS];
        const int idx = blk - BB * KCH;   // 0..127
        const int b = idx >> 1;
        const int half = idx & 1;
        ((float4*)q_sh)[t] = ((const float4*)queries)[(size_t)b * S4 + t];
        __syncthreads();
        const int wid = t >> 6, lane = t & 63;
        const int rbase = half * 64 + wid * 16;
        #pragma unroll
        for (int i = 0; i < 16; ++i) {
            const int r = rbase + i;      // 0..127
            const float4* w4 = (const float4*)(W1 + (size_t)r * SS);
            float sum = 0.f;
            #pragma unroll
            for (int j = 0; j < 4; ++j)
                sum += dot4(w4[lane + 64 * j], ((const float4*)q_sh)[lane + 64 * j]);
            #pragma unroll
            for (int off = 32; off > 0; off >>= 1)
                sum += __shfl_down(sum, off, 64);
            if (lane == 0) uo[(size_t)b * 256 + r] = sum;
        }
    }
}

// ---------------------------------------------------------------------------
// Kernel 2: o rows — uo[b][128+r] = dot(W2[r], ssum[b]), ssum reduced in-block.
// grid = 64*8 = 512 blocks, 256 threads (4 waves x 4 rows).
// ---------------------------------------------------------------------------
__global__ __launch_bounds__(256) void k_o(
    const float4* __restrict__ partial, const float* __restrict__ W2,
    float* __restrict__ uo) {
    __shared__ float s_sh[SS];
    const int b = blockIdx.x >> 3;
    const int chunk = blockIdx.x & 7;
    const int t = threadIdx.x;
    const int S4 = SS / 4;

    float4 acc = make_float4(0.f, 0.f, 0.f, 0.f);
    #pragma unroll
    for (int k = 0; k < KCH; ++k) {
        float4 v = partial[(size_t)(k * BB + b) * S4 + t];
        acc.x += v.x; acc.y += v.y; acc.z += v.z; acc.w += v.w;
    }
    ((float4*)s_sh)[t] = acc;
    __syncthreads();

    const int wid = t >> 6, lane = t & 63;
    const int rbase = chunk * 16 + wid * 4;
    #pragma unroll
    for (int i = 0; i < 4; ++i) {
        const int r = rbase + i;          // 0..127
        const float4* w4 = (const float4*)(W2 + (size_t)r * SS);
        float sum = 0.f;
        #pragma unroll
        for (int j = 0; j < 4; ++j)
            sum += dot4(w4[lane + 64 * j], ((const float4*)s_sh)[lane + 64 * j]);
        #pragma unroll
        for (int off = 32; off > 0; off >>= 1)
            sum += __shfl_down(sum, off, 64);
        if (lane == 0) uo[(size_t)b * 256 + EE + r] = sum;
    }
}

// ---------------------------------------------------------------------------
// Kernel 3: 3 hops: v = o + W3@u; u = v/max(||v||,eps). grid=BB, 128 threads.
// ---------------------------------------------------------------------------
__global__ __launch_bounds__(128) void k_hops(
    const float* __restrict__ W3, const float* __restrict__ uo,
    float* __restrict__ u_out) {
    __shared__ float u_sh[EE];
    __shared__ float red[2];
    const int b = blockIdx.x, t = threadIdx.x;
    const int wid = t >> 6, lane = t & 63;

    const float o_r = uo[(size_t)b * 256 + EE + t];
    u_sh[t] = uo[(size_t)b * 256 + t];
    __syncthreads();

    const float4* w4 = (const float4*)(W3 + (size_t)t * EE);
    float u_new = 0.f;
    for (int hop = 0; hop < 3; ++hop) {
        float sum = 0.f;
        #pragma unroll
        for (int j = 0; j < EE / 4; ++j)
            sum += dot4(w4[j], ((const float4*)u_sh)[j]);
        const float v = o_r + sum;
        float s2 = v * v;
        #pragma unroll
        for (int off = 32; off > 0; off >>= 1)
            s2 += __shfl_down(s2, off, 64);
        if (lane == 0) red[wid] = s2;
        __syncthreads();                       // dots done + red visible
        const float rn = 1.0f / fmaxf(sqrtf(red[0] + red[1]), 1e-12f);
        u_new = v * rn;
        u_sh[t] = u_new;
        __syncthreads();                       // u_sh updated for next hop
    }
    u_out[(size_t)b * EE + t] = u_new;
}

// ---------------------------------------------------------------------------
// Kernel 4: logits[b][c] = dot(u[b], W4[c])   [64 x 10000]
// grid = 625 blocks (16 classes each, exact), 128 threads. 2c x 4b register
// tile: 8 dot4 per (2 global + 4 LDS) float4 loads; 1250 waves / 1024 SIMDs.
// ---------------------------------------------------------------------------
__global__ __launch_bounds__(128) void k_logits(
    const float* __restrict__ u_all, const float* __restrict__ W4,
    float* __restrict__ logits) {
    __shared__ float u_sh[BB * 132];
    const int t = threadIdx.x;

    {
        const float4* ug = (const float4*)u_all;
        for (int i = t; i < BB * (EE / 4); i += 128) {
            int bb = i >> 5, e4 = i & 31;
            ((float4*)(u_sh + bb * 132))[e4] = ug[i];
        }
    }
    __syncthreads();

    const int bg = t & 15;   // b = bg + 16*j
    const int cg = t >> 4;   // 0..7
    const int cbase = blockIdx.x * CTILE + cg * 2;   // always < CC-1

    const float4* wr0 = (const float4*)(W4 + (size_t)(cbase + 0) * EE);
    const float4* wr1 = (const float4*)(W4 + (size_t)(cbase + 1) * EE);
    const float4* u0 = (const float4*)(u_sh + (bg + 0)  * 132);
    const float4* u1 = (const float4*)(u_sh + (bg + 16) * 132);
    const float4* u2 = (const float4*)(u_sh + (bg + 32) * 132);
    const float4* u3 = (const float4*)(u_sh + (bg + 48) * 132);

    float acc[2][4];
    #pragma unroll
    for (int i = 0; i < 2; ++i)
        #pragma unroll
        for (int j = 0; j < 4; ++j) acc[i][j] = 0.f;

    #pragma unroll 8
    for (int e4 = 0; e4 < EE / 4; ++e4) {
        float4 w0 = wr0[e4], w1 = wr1[e4];
        float4 x0 = u0[e4], x1 = u1[e4], x2 = u2[e4], x3 = u3[e4];
        acc[0][0] += dot4(w0, x0); acc[0][1] += dot4(w0, x1);
        acc[0][2] += dot4(w0, x2); acc[0][3] += dot4(w0, x3);
        acc[1][0] += dot4(w1, x0); acc[1][1] += dot4(w1, x1);
        acc[1][2] += dot4(w1, x2); acc[1][3] += dot4(w1, x3);
    }

    #pragma unroll
    for (int i = 0; i < 2; ++i) {
        #pragma unroll
        for (int j = 0; j < 4; ++j) {
            int bb = bg + 16 * j;
            logits[(size_t)bb * CC + cbase + i] = acc[i][j];
        }
    }
}

// ---------------------------------------------------------------------------
// Kernel 5: row softmax over CC. grid = BB blocks, 1024 threads (16 waves).
// Row staged in LDS (40 KB): max -> exp+sum -> scale, single global RW pass.
// ---------------------------------------------------------------------------
__global__ __launch_bounds__(1024) void k_softmax(
    const float* __restrict__ logits, float* __restrict__ out) {
    __shared__ float row[CC];
    __shared__ float redm[16];
    __shared__ float reds[16];
    const int b = blockIdx.x, t = threadIdx.x;
    const int wid = t >> 6, lane = t & 63;
    const int C4 = CC / 4;  // 2500

    const float4* src = (const float4*)(logits + (size_t)b * CC);
    float4* row4 = (float4*)row;

    float lmax = -3.4e38f;
    for (int i = t; i < C4; i += 1024) {
        float4 v = src[i];
        row4[i] = v;
        lmax = fmaxf(lmax, fmaxf(fmaxf(v.x, v.y), fmaxf(v.z, v.w)));
    }
    #pragma unroll
    for (int off = 32; off > 0; off >>= 1)
        lmax = fmaxf(lmax, __shfl_down(lmax, off, 64));
    if (lane == 0) redm[wid] = lmax;
    __syncthreads();
    float m = redm[0];
    #pragma unroll
    for (int k = 1; k < 16; ++k) m = fmaxf(m, redm[k]);

    float lsum = 0.f;
    for (int i = t; i < C4; i += 1024) {
        float4 v = row4[i];
        v.x = expf(v.x - m); v.y = expf(v.y - m);
        v.z = expf(v.z - m); v.w = expf(v.w - m);
        row4[i] = v;
        lsum += (v.x + v.y) + (v.z + v.w);
    }
    #pragma unroll
    for (int off = 32; off > 0; off >>= 1)
        lsum += __shfl_down(lsum, off, 64);
    if (lane == 0) reds[wid] = lsum;
    __syncthreads();
    float s = 0.f;
    #pragma unroll
    for (int k = 0; k < 16; ++k) s += reds[k];
    const float inv = 1.0f / s;

    float4* dst = (float4*)(out + (size_t)b * CC);
    for (int i = t; i < C4; i += 1024) {
        float4 v = row4[i];
        v.x *= inv; v.y *= inv; v.z *= inv; v.w *= inv;
        dst[i] = v;
    }
}

// ---------------------------------------------------------------------------
extern "C" void kernel_launch(void* const* d_in, const int* in_sizes, int n_in,
                              void* d_out, int out_size, void* d_ws, size_t ws_size,
                              hipStream_t stream) {
    const float* stories = (const float*)d_in[0];
    const float* queries = (const float*)d_in[1];
    const float* W1 = (const float*)d_in[2];
    const float* W2 = (const float*)d_in[3];
    const float* W3 = (const float*)d_in[4];
    const float* W4 = (const float*)d_in[5];
    float* out = (float*)d_out;

    // ws layout (floats):
    // partial[KCH][BB][SS] | uo[BB][256] | u_all[BB][EE] | logits[BB][CC]
    float* partial = (float*)d_ws;
    float* uo      = partial + (size_t)KCH * BB * SS;   // +4 MB
    float* u_all   = uo + (size_t)BB * 256;             // +64 KB
    float* logits  = u_all + (size_t)BB * EE;           // +32 KB

    k_stories_u0<<<BB * KCH + 128, 256, 0, stream>>>(
        (const float4*)stories, (float4*)partial, queries, W1, uo);
    k_o<<<BB * 8, 256, 0, stream>>>((const float4*)partial, W2, uo);
    k_hops<<<BB, 128, 0, stream>>>(W3, uo, u_all);
    k_logits<<<CC / CTILE, 128, 0, stream>>>(u_all, W4, logits);
    k_softmax<<<BB, 1024, 0, stream>>>(logits, out);
}

// Round 6
// 236.002 us; speedup vs baseline: 1.0061x; 1.0061x over previous
//
#include <hip/hip_runtime.h>
#include <hip/hip_bf16.h>

#define BB   64      // batch
#define MM   512     // memories
#define SS   1024    // story len
#define EE   128     // embed
#define CC   10000   // classes
#define KCH  16      // m-chunks for stories reduction
#define MCH  (MM / KCH)   // 32 rows per chunk
#define CTILE 16     // classes per block in logits kernel (10000 = 625*16)

__device__ __forceinline__ float dot4(const float4 a, const float4 b) {
    return a.x * b.x + a.y * b.y + a.z * b.z + a.w * b.w;
}

// ---------------------------------------------------------------------------
// Kernel 1: blocks [0,1024): partial[k][b][s] = sum over m-chunk k of stories.
//           blocks [1024,1152): u0 rows — uo[b][r] = dot(W1[r], q[b]).
// The u0 compute (8.4M MAC, L2-resident W1) hides under the 134 MB HBM stream.
// ---------------------------------------------------------------------------
__global__ __launch_bounds__(256) void k_stories_u0(
    const float4* __restrict__ stories, float4* __restrict__ partial,
    const float* __restrict__ queries, const float* __restrict__ W1,
    float* __restrict__ uo) {
    const int S4 = SS / 4;  // 256
    const int blk = blockIdx.x;
    const int t = threadIdx.x;

    if (blk < BB * KCH) {
        const int b = blk >> 4;          // / KCH
        const int k = blk & (KCH - 1);
        const float4* src = stories + ((size_t)(b * MM + k * MCH) * S4 + t);
        float4 a0 = make_float4(0.f, 0.f, 0.f, 0.f);
        float4 a1 = a0, a2 = a0, a3 = a0;
        #pragma unroll
        for (int m = 0; m < MCH; m += 4) {
            float4 x0 = src[(size_t)(m + 0) * S4];
            float4 x1 = src[(size_t)(m + 1) * S4];
            float4 x2 = src[(size_t)(m + 2) * S4];
            float4 x3 = src[(size_t)(m + 3) * S4];
            a0.x += x0.x; a0.y += x0.y; a0.z += x0.z; a0.w += x0.w;
            a1.x += x1.x; a1.y += x1.y; a1.z += x1.z; a1.w += x1.w;
            a2.x += x2.x; a2.y += x2.y; a2.z += x2.z; a2.w += x2.w;
            a3.x += x3.x; a3.y += x3.y; a3.z += x3.z; a3.w += x3.w;
        }
        float4 r;
        r.x = (a0.x + a1.x) + (a2.x + a3.x);
        r.y = (a0.y + a1.y) + (a2.y + a3.y);
        r.z = (a0.z + a1.z) + (a2.z + a3.z);
        r.w = (a0.w + a1.w) + (a2.w + a3.w);
        partial[(size_t)(k * BB + b) * S4 + t] = r;
    } else {
        __shared__ float q_sh[SS];
        const int idx = blk - BB * KCH;   // 0..127
        const int b = idx >> 1;
        const int half = idx & 1;
        ((float4*)q_sh)[t] = ((const float4*)queries)[(size_t)b * S4 + t];
        __syncthreads();
        const int wid = t >> 6, lane = t & 63;
        const int rbase = half * 64 + wid * 16;
        #pragma unroll
        for (int i = 0; i < 16; ++i) {
            const int r = rbase + i;      // 0..127
            const float4* w4 = (const float4*)(W1 + (size_t)r * SS);
            float sum = 0.f;
            #pragma unroll
            for (int j = 0; j < 4; ++j)
                sum += dot4(w4[lane + 64 * j], ((const float4*)q_sh)[lane + 64 * j]);
            #pragma unroll
            for (int off = 32; off > 0; off >>= 1)
                sum += __shfl_down(sum, off, 64);
            if (lane == 0) uo[(size_t)b * 256 + r] = sum;
        }
    }
}

// ---------------------------------------------------------------------------
// Kernel 2: ssum[b][s] = sum_k partial[k][b][s]. grid = 256 blocks x 64 thr.
// Collapses the 16 partials once (8 MB read total) so k_o stages 4 KB/block.
// ---------------------------------------------------------------------------
__global__ __launch_bounds__(64) void k_ssum(
    const float4* __restrict__ partial, float4* __restrict__ ssum) {
    const int S4 = SS / 4;
    const int b = blockIdx.x >> 2;
    const int col = (blockIdx.x & 3) * 64 + threadIdx.x;   // 0..255
    float4 acc = make_float4(0.f, 0.f, 0.f, 0.f);
    #pragma unroll
    for (int k = 0; k < KCH; ++k) {
        float4 v = partial[(size_t)(k * BB + b) * S4 + col];
        acc.x += v.x; acc.y += v.y; acc.z += v.z; acc.w += v.w;
    }
    ssum[(size_t)b * S4 + col] = acc;
}

// ---------------------------------------------------------------------------
// Kernel 3: o rows — uo[b][128+r] = dot(W2[r], ssum[b]).
// grid = 64*8 = 512 blocks (b, 16-row chunk), 256 threads (4 waves x 4 rows).
// ---------------------------------------------------------------------------
__global__ __launch_bounds__(256) void k_o(
    const float* __restrict__ ssum, const float* __restrict__ W2,
    float* __restrict__ uo) {
    __shared__ float s_sh[SS];
    const int b = blockIdx.x >> 3;
    const int chunk = blockIdx.x & 7;
    const int t = threadIdx.x;
    const int S4 = SS / 4;

    ((float4*)s_sh)[t] = ((const float4*)ssum)[(size_t)b * S4 + t];
    __syncthreads();

    const int wid = t >> 6, lane = t & 63;
    const int rbase = chunk * 16 + wid * 4;
    #pragma unroll
    for (int i = 0; i < 4; ++i) {
        const int r = rbase + i;          // 0..127
        const float4* w4 = (const float4*)(W2 + (size_t)r * SS);
        float sum = 0.f;
        #pragma unroll
        for (int j = 0; j < 4; ++j)
            sum += dot4(w4[lane + 64 * j], ((const float4*)s_sh)[lane + 64 * j]);
        #pragma unroll
        for (int off = 32; off > 0; off >>= 1)
            sum += __shfl_down(sum, off, 64);
        if (lane == 0) uo[(size_t)b * 256 + EE + r] = sum;
    }
}

// ---------------------------------------------------------------------------
// Kernel 4: 3 hops: v = o + W3@u; u = v/max(||v||,eps). grid=BB, 128 threads.
// ---------------------------------------------------------------------------
__global__ __launch_bounds__(128) void k_hops(
    const float* __restrict__ W3, const float* __restrict__ uo,
    float* __restrict__ u_out) {
    __shared__ float u_sh[EE];
    __shared__ float red[2];
    const int b = blockIdx.x, t = threadIdx.x;
    const int wid = t >> 6, lane = t & 63;

    const float o_r = uo[(size_t)b * 256 + EE + t];
    u_sh[t] = uo[(size_t)b * 256 + t];
    __syncthreads();

    const float4* w4 = (const float4*)(W3 + (size_t)t * EE);
    float u_new = 0.f;
    for (int hop = 0; hop < 3; ++hop) {
        float sum = 0.f;
        #pragma unroll
        for (int j = 0; j < EE / 4; ++j)
            sum += dot4(w4[j], ((const float4*)u_sh)[j]);
        const float v = o_r + sum;
        float s2 = v * v;
        #pragma unroll
        for (int off = 32; off > 0; off >>= 1)
            s2 += __shfl_down(s2, off, 64);
        if (lane == 0) red[wid] = s2;
        __syncthreads();                       // dots done + red visible
        const float rn = 1.0f / fmaxf(sqrtf(red[0] + red[1]), 1e-12f);
        u_new = v * rn;
        u_sh[t] = u_new;
        __syncthreads();                       // u_sh updated for next hop
    }
    u_out[(size_t)b * EE + t] = u_new;
}

// ---------------------------------------------------------------------------
// Kernel 5: logits[b][c] = dot(u[b], W4[c])   [64 x 10000]
// grid = 625 blocks (16 classes each, exact), 128 threads. 2c x 4b register
// tile: 8 dot4 per (2 global + 4 LDS) float4 loads; 1250 waves / 1024 SIMDs.
// ---------------------------------------------------------------------------
__global__ __launch_bounds__(128) void k_logits(
    const float* __restrict__ u_all, const float* __restrict__ W4,
    float* __restrict__ logits) {
    __shared__ float u_sh[BB * 132];
    const int t = threadIdx.x;

    {
        const float4* ug = (const float4*)u_all;
        for (int i = t; i < BB * (EE / 4); i += 128) {
            int bb = i >> 5, e4 = i & 31;
            ((float4*)(u_sh + bb * 132))[e4] = ug[i];
        }
    }
    __syncthreads();

    const int bg = t & 15;   // b = bg + 16*j
    const int cg = t >> 4;   // 0..7
    const int cbase = blockIdx.x * CTILE + cg * 2;   // always < CC-1

    const float4* wr0 = (const float4*)(W4 + (size_t)(cbase + 0) * EE);
    const float4* wr1 = (const float4*)(W4 + (size_t)(cbase + 1) * EE);
    const float4* u0 = (const float4*)(u_sh + (bg + 0)  * 132);
    const float4* u1 = (const float4*)(u_sh + (bg + 16) * 132);
    const float4* u2 = (const float4*)(u_sh + (bg + 32) * 132);
    const float4* u3 = (const float4*)(u_sh + (bg + 48) * 132);

    float acc[2][4];
    #pragma unroll
    for (int i = 0; i < 2; ++i)
        #pragma unroll
        for (int j = 0; j < 4; ++j) acc[i][j] = 0.f;

    #pragma unroll 8
    for (int e4 = 0; e4 < EE / 4; ++e4) {
        float4 w0 = wr0[e4], w1 = wr1[e4];
        float4 x0 = u0[e4], x1 = u1[e4], x2 = u2[e4], x3 = u3[e4];
        acc[0][0] += dot4(w0, x0); acc[0][1] += dot4(w0, x1);
        acc[0][2] += dot4(w0, x2); acc[0][3] += dot4(w0, x3);
        acc[1][0] += dot4(w1, x0); acc[1][1] += dot4(w1, x1);
        acc[1][2] += dot4(w1, x2); acc[1][3] += dot4(w1, x3);
    }

    #pragma unroll
    for (int i = 0; i < 2; ++i) {
        #pragma unroll
        for (int j = 0; j < 4; ++j) {
            int bb = bg + 16 * j;
            logits[(size_t)bb * CC + cbase + i] = acc[i][j];
        }
    }
}

// ---------------------------------------------------------------------------
// Kernel 6: row softmax over CC. grid = BB blocks, 1024 threads (16 waves).
// Row staged in LDS (40 KB): max -> exp+sum -> scale, single global RW pass.
// ---------------------------------------------------------------------------
__global__ __launch_bounds__(1024) void k_softmax(
    const float* __restrict__ logits, float* __restrict__ out) {
    __shared__ float row[CC];
    __shared__ float redm[16];
    __shared__ float reds[16];
    const int b = blockIdx.x, t = threadIdx.x;
    const int wid = t >> 6, lane = t & 63;
    const int C4 = CC / 4;  // 2500

    const float4* src = (const float4*)(logits + (size_t)b * CC);
    float4* row4 = (float4*)row;

    float lmax = -3.4e38f;
    for (int i = t; i < C4; i += 1024) {
        float4 v = src[i];
        row4[i] = v;
        lmax = fmaxf(lmax, fmaxf(fmaxf(v.x, v.y), fmaxf(v.z, v.w)));
    }
    #pragma unroll
    for (int off = 32; off > 0; off >>= 1)
        lmax = fmaxf(lmax, __shfl_down(lmax, off, 64));
    if (lane == 0) redm[wid] = lmax;
    __syncthreads();
    float m = redm[0];
    #pragma unroll
    for (int k = 1; k < 16; ++k) m = fmaxf(m, redm[k]);

    float lsum = 0.f;
    for (int i = t; i < C4; i += 1024) {
        float4 v = row4[i];
        v.x = expf(v.x - m); v.y = expf(v.y - m);
        v.z = expf(v.z - m); v.w = expf(v.w - m);
        row4[i] = v;
        lsum += (v.x + v.y) + (v.z + v.w);
    }
    #pragma unroll
    for (int off = 32; off > 0; off >>= 1)
        lsum += __shfl_down(lsum, off, 64);
    if (lane == 0) reds[wid] = lsum;
    __syncthreads();
    float s = 0.f;
    #pragma unroll
    for (int k = 0; k < 16; ++k) s += reds[k];
    const float inv = 1.0f / s;

    float4* dst = (float4*)(out + (size_t)b * CC);
    for (int i = t; i < C4; i += 1024) {
        float4 v = row4[i];
        v.x *= inv; v.y *= inv; v.z *= inv; v.w *= inv;
        dst[i] = v;
    }
}

// ---------------------------------------------------------------------------
extern "C" void kernel_launch(void* const* d_in, const int* in_sizes, int n_in,
                              void* d_out, int out_size, void* d_ws, size_t ws_size,
                              hipStream_t stream) {
    const float* stories = (const float*)d_in[0];
    const float* queries = (const float*)d_in[1];
    const float* W1 = (const float*)d_in[2];
    const float* W2 = (const float*)d_in[3];
    const float* W3 = (const float*)d_in[4];
    const float* W4 = (const float*)d_in[5];
    float* out = (float*)d_out;

    // ws layout (floats):
    // partial[KCH][BB][SS] | ssum[BB][SS] | uo[BB][256] | u_all[BB][EE] | logits[BB][CC]
    float* partial = (float*)d_ws;
    float* ssum    = partial + (size_t)KCH * BB * SS;   // +4 MB
    float* uo      = ssum + (size_t)BB * SS;            // +256 KB
    float* u_all   = uo + (size_t)BB * 256;             // +64 KB
    float* logits  = u_all + (size_t)BB * EE;           // +32 KB

    k_stories_u0<<<BB * KCH + 128, 256, 0, stream>>>(
        (const float4*)stories, (float4*)partial, queries, W1, uo);
    k_ssum<<<BB * 4, 64, 0, stream>>>((const float4*)partial, (float4*)ssum);
    k_o<<<BB * 8, 256, 0, stream>>>(ssum, W2, uo);
    k_hops<<<BB, 128, 0, stream>>>(W3, uo, u_all);
    k_logits<<<CC / CTILE, 128, 0, stream>>>(u_all, W4, logits);
    k_softmax<<<BB, 1024, 0, stream>>>(logits, out);
}